// Round 2
// baseline (744.342 us; speedup 1.0000x reference)
//
#include <hip/hip_runtime.h>
#include <stdint.h>
#include <math.h>

#define DEV static __device__ __forceinline__

typedef __attribute__((ext_vector_type(8))) short short8;
typedef __attribute__((ext_vector_type(4))) float f32x4;

#define B_ 4
#define T_ 2048
#define H_ 16
#define KVH_ 4
#define HD_ 128
#define DIM_ 2048
#define KVD_ 512

DEV float bf2f(unsigned short h) {
  union { uint32_t u; float f; } v; v.u = ((uint32_t)h) << 16; return v.f;
}
DEV unsigned short f2bf(float f) {
  uint32_t u = __builtin_bit_cast(uint32_t, f);
  u += 0x7fffu + ((u >> 16) & 1u);   // round-to-nearest-even
  return (unsigned short)(u >> 16);
}
DEV void gll16(const void* g, void* l) {
  __builtin_amdgcn_global_load_lds(
      (const __attribute__((address_space(1))) unsigned int*)g,
      (__attribute__((address_space(3))) unsigned int*)l, 16, 0, 0);
}

// ---------------- fp32 -> bf16 convert (vectorized) ----------------
__global__ __launch_bounds__(256) void cvt_f32_bf16(
    const float* __restrict__ in, unsigned short* __restrict__ out) {
  size_t idx = ((size_t)blockIdx.x * 256 + threadIdx.x) * 8;
  float4 a = *(const float4*)(in + idx);
  float4 b = *(const float4*)(in + idx + 4);
  short8 o;
  o[0] = (short)f2bf(a.x); o[1] = (short)f2bf(a.y);
  o[2] = (short)f2bf(a.z); o[3] = (short)f2bf(a.w);
  o[4] = (short)f2bf(b.x); o[5] = (short)f2bf(b.y);
  o[6] = (short)f2bf(b.z); o[7] = (short)f2bf(b.w);
  *(short8*)(out + idx) = o;
}

// ---------------- transpose + convert: W fp32 [R][C] -> Wt bf16 [C][R] ----------------
__global__ __launch_bounds__(256) void transpose_f32_bf16(
    const float* __restrict__ W, unsigned short* __restrict__ Wt,
    int R, int C) {
  __shared__ float t[32][33];
  int c0 = blockIdx.x * 32, r0 = blockIdx.y * 32;
  int col = threadIdx.x & 31;
  int rr = (threadIdx.x >> 5) * 4;
#pragma unroll
  for (int i = 0; i < 4; ++i)
    t[rr + i][col] = W[(size_t)(r0 + rr + i) * C + c0 + col];
  __syncthreads();
#pragma unroll
  for (int i = 0; i < 4; ++i)
    Wt[(size_t)(c0 + rr + i) * R + r0 + col] = f2bf(t[col][rr + i]);
}

// ---------------- RoPE in-place (bf16); one wave per head-row ----------------
__global__ __launch_bounds__(256) void rope_kernel(unsigned short* q,
                                                   unsigned short* k) {
  int wid = blockIdx.x * 4 + (threadIdx.x >> 6);
  int lane = threadIdx.x & 63;
  const int NQ = B_ * T_ * H_;
  unsigned short* ptr;
  int t;
  if (wid < NQ) {
    int bt = wid >> 4, h = wid & (H_ - 1);
    ptr = q + (size_t)bt * DIM_ + h * HD_;
    t = bt & (T_ - 1);
  } else {
    int id = wid - NQ;
    int bt = id >> 2, g = id & (KVH_ - 1);
    ptr = k + (size_t)bt * KVD_ + g * HD_;
    t = bt & (T_ - 1);
  }
  float inv = __expf(-(float)lane * 0.14391157f);  // ln(10000)/64
  float ang = (float)t * inv;
  float s = sinf(ang), c = cosf(ang);              // precise range reduction
  uint32_t zz = *(const uint32_t*)(ptr + lane * 2);
  float z1 = bf2f((unsigned short)(zz & 0xffff));
  float z2 = bf2f((unsigned short)(zz >> 16));
  unsigned short o1 = f2bf(z1 * c - z2 * s);
  unsigned short o2 = f2bf(z1 * s + z2 * c);
  ptr[lane] = o1;
  ptr[64 + lane] = o2;
}

// ---------------- GEMM: C[M,N] = A[M,K] @ Bt[N,K]^T  (m97 structure) ----------------
// 128x128 tile, BK=32, 4 waves 2x2, 16x16x32 MFMA, global_load_lds width 16.
// OUT_F32: store fp32 (final projection) vs bf16 (intermediates).
template <bool OUT_F32>
__global__ __launch_bounds__(256) void gemm_bt(
    const unsigned short* __restrict__ A, const unsigned short* __restrict__ Bt,
    void* __restrict__ Cout, int M, int N, int K) {
  __shared__ unsigned short As[128 * 32];
  __shared__ unsigned short Bs[128 * 32];
  int m0 = blockIdx.y * 128, n0 = blockIdx.x * 128;
  int tid = threadIdx.x, w = tid >> 6, l = tid & 63;
  int wr = w >> 1, wc = w & 1;
  int l15 = l & 15, l4 = l >> 4;
  f32x4 acc[4][4] = {};
  for (int k0 = 0; k0 < K; k0 += 32) {
    __syncthreads();
#pragma unroll
    for (int i = 0; i < 2; ++i) {
      int u = i * 256 + w * 64 + l;          // lane-contiguous LDS units
      int row = u >> 2, kc = u & 3;
      gll16(A + (size_t)(m0 + row) * K + k0 + kc * 8, As + (size_t)u * 8);
      gll16(Bt + (size_t)(n0 + row) * K + k0 + kc * 8, Bs + (size_t)u * 8);
    }
    __syncthreads();
    short8 a[4], b[4];
#pragma unroll
    for (int mb = 0; mb < 4; ++mb)
      a[mb] = *(const short8*)(As + ((wr * 64 + mb * 16 + l15) * 4 + l4) * 8);
#pragma unroll
    for (int nb = 0; nb < 4; ++nb)
      b[nb] = *(const short8*)(Bs + ((wc * 64 + nb * 16 + l15) * 4 + l4) * 8);
#pragma unroll
    for (int mb = 0; mb < 4; ++mb)
#pragma unroll
      for (int nb = 0; nb < 4; ++nb)
        acc[mb][nb] =
            __builtin_amdgcn_mfma_f32_16x16x32_bf16(a[mb], b[nb], acc[mb][nb], 0, 0, 0);
  }
#pragma unroll
  for (int mb = 0; mb < 4; ++mb)
#pragma unroll
    for (int nb = 0; nb < 4; ++nb)
#pragma unroll
      for (int r = 0; r < 4; ++r) {
        size_t off = (size_t)(m0 + wr * 64 + mb * 16 + l4 * 4 + r) * N +
                     n0 + wc * 64 + nb * 16 + l15;
        if (OUT_F32)
          ((float*)Cout)[off] = acc[mb][nb][r];
        else
          ((unsigned short*)Cout)[off] = f2bf(acc[mb][nb][r]);
      }
}

// ---------------- Flash attention (causal, GQA 4:1) ----------------
// grid: x = q-tile (64 rows), y = b*H + h. 4 waves, each owns 16 q rows.
// K tile [64][128] LDS, XOR-swizzled via pre-swizzled global source (gll).
// V tile transposed to Vt[128][64], XOR-swizzled. P via per-wave LDS.
__global__ __launch_bounds__(256) void attn_kernel(
    const unsigned short* qws, const unsigned short* __restrict__ kws,
    const unsigned short* __restrict__ vws, unsigned short* ows) {
  int qt = blockIdx.x, bh = blockIdx.y;
  int b = bh >> 4, h = bh & 15, g = h >> 2;
  int tid = threadIdx.x, w = tid >> 6, l = tid & 63;
  int l15 = l & 15, l4 = l >> 4;

  __shared__ unsigned short Ks[64 * 128];
  __shared__ unsigned short Vt[128 * 64];
  __shared__ unsigned short Ps[4][16 * 64];

  int q0w = qt * 64 + w * 16;
  short8 qf[4];
  {
    const unsigned short* qrow =
        qws + (size_t)(b * T_ + q0w + l15) * DIM_ + h * HD_ + l4 * 8;
#pragma unroll
    for (int kc = 0; kc < 4; ++kc) qf[kc] = *(const short8*)(qrow + kc * 32);
  }
  f32x4 o[8] = {};
  float m_r[4], l_r[4];
#pragma unroll
  for (int r = 0; r < 4; ++r) { m_r[r] = -INFINITY; l_r[r] = 0.f; }
  const float scale = 0.088388347648318447f;  // 1/sqrt(128)

  for (int kt = 0; kt <= qt; ++kt) {
    int kv0 = kt * 64;
    __syncthreads();
    // stage K: linear LDS dest, swizzled (gathered) global source
#pragma unroll
    for (int i = 0; i < 4; ++i) {
      int u = (i * 4 + w) * 64 + l;
      int row = u >> 4, c = u & 15;
      int kc = c ^ (row & 15);
      gll16(kws + (size_t)(b * T_ + kv0 + row) * KVD_ + g * HD_ + kc * 8,
            Ks + (size_t)u * 8);
    }
    // stage V transposed (reg-staged), swizzled
    {
      int kv = tid & 63;
      const unsigned short* vrow = vws + (size_t)(b * T_ + kv0 + kv) * KVD_ + g * HD_;
#pragma unroll
      for (int i = 0; i < 4; ++i) {
        int dc = w + i * 4;
        short8 v8 = *(const short8*)(vrow + dc * 8);
#pragma unroll
        for (int j = 0; j < 8; ++j)
          Vt[(dc * 8 + j) * 64 + (((kv >> 3) ^ j) << 3) + (kv & 7)] =
              (unsigned short)v8[j];
      }
    }
    __syncthreads();
    // S = Q K^T : D rows q=(l>>4)*4+r, cols kv=nb*16+l15
    f32x4 s[4];
#pragma unroll
    for (int nb = 0; nb < 4; ++nb) {
      f32x4 acc = {};
#pragma unroll
      for (int kc = 0; kc < 4; ++kc) {
        int row = nb * 16 + l15;
        int c8 = (kc * 4 + l4) ^ (row & 15);
        short8 kf = *(const short8*)(Ks + (row * 16 + c8) * 8);
        acc = __builtin_amdgcn_mfma_f32_16x16x32_bf16(qf[kc], kf, acc, 0, 0, 0);
      }
      s[nb] = acc;
    }
    bool diag = (kt == qt);
#pragma unroll
    for (int nb = 0; nb < 4; ++nb)
#pragma unroll
      for (int r = 0; r < 4; ++r) {
        float v = s[nb][r] * scale;
        if (diag && (nb * 16 + l15) > (w * 16 + l4 * 4 + r)) v = -1e30f;
        s[nb][r] = v;
      }
    // online softmax; row group = 16 lanes sharing l>>4
#pragma unroll
    for (int r = 0; r < 4; ++r) {
      float mx = fmaxf(fmaxf(s[0][r], s[1][r]), fmaxf(s[2][r], s[3][r]));
      mx = fmaxf(mx, __shfl_xor(mx, 1));
      mx = fmaxf(mx, __shfl_xor(mx, 2));
      mx = fmaxf(mx, __shfl_xor(mx, 4));
      mx = fmaxf(mx, __shfl_xor(mx, 8));
      float mnew = fmaxf(m_r[r], mx);
      float alpha = __expf(m_r[r] - mnew);
      m_r[r] = mnew;
      float sum = 0.f;
#pragma unroll
      for (int nb = 0; nb < 4; ++nb) {
        float p = __expf(s[nb][r] - mnew);
        s[nb][r] = p;
        sum += p;
      }
      sum += __shfl_xor(sum, 1);
      sum += __shfl_xor(sum, 2);
      sum += __shfl_xor(sum, 4);
      sum += __shfl_xor(sum, 8);
      l_r[r] = l_r[r] * alpha + sum;
#pragma unroll
      for (int db = 0; db < 8; ++db) o[db][r] *= alpha;
    }
    // P -> per-wave LDS (swizzled), then PV
    unsigned short* pws = Ps[w];
#pragma unroll
    for (int nb = 0; nb < 4; ++nb)
#pragma unroll
      for (int r = 0; r < 4; ++r) {
        int q = l4 * 4 + r;
        int kv = nb * 16 + l15;
        pws[q * 64 + (((kv >> 3) ^ (q & 7)) << 3) + (kv & 7)] = f2bf(s[nb][r]);
      }
#pragma unroll
    for (int ks = 0; ks < 2; ++ks) {
      short8 pa = *(const short8*)(pws + l15 * 64 + (((ks * 4 + l4) ^ (l15 & 7)) << 3));
#pragma unroll
      for (int db = 0; db < 8; ++db) {
        int d = db * 16 + l15;
        short8 vb = *(const short8*)(Vt + d * 64 + (((ks * 4 + l4) ^ (d & 7)) << 3));
        o[db] = __builtin_amdgcn_mfma_f32_16x16x32_bf16(pa, vb, o[db], 0, 0, 0);
      }
    }
  }
  // epilogue: normalize and store (row-major [B*T, DIM], aliases q_ws safely:
  // each block reads exactly the region it later writes, read-before-write)
#pragma unroll
  for (int r = 0; r < 4; ++r) {
    float invl = 1.f / l_r[r];
    unsigned short* orow =
        ows + (size_t)(b * T_ + q0w + l4 * 4 + r) * DIM_ + h * HD_;
#pragma unroll
    for (int db = 0; db < 8; ++db) orow[db * 16 + l15] = f2bf(o[db][r] * invl);
  }
}

// ---------------- launch ----------------
extern "C" void kernel_launch(void* const* d_in, const int* in_sizes, int n_in,
                              void* d_out, int out_size, void* d_ws, size_t ws_size,
                              hipStream_t stream) {
  (void)in_sizes; (void)n_in; (void)out_size; (void)ws_size;
  const float* x  = (const float*)d_in[0];
  const float* Wq = (const float*)d_in[1];
  const float* Wk = (const float*)d_in[2];
  const float* Wv = (const float*)d_in[3];
  const float* Wo = (const float*)d_in[4];
  float* out = (float*)d_out;
  char* ws = (char*)d_ws;
  // ws layout (bytes): q/attn 32MB | k 8MB | v 8MB | Wqt 8MB | Wkt 2MB | Wvt 2MB | Wot 8MB = 68MB
  unsigned short* q_ws = (unsigned short*)(ws + 0);
  unsigned short* k_ws = (unsigned short*)(ws + 33554432);
  unsigned short* v_ws = (unsigned short*)(ws + 41943040);
  unsigned short* Wqt  = (unsigned short*)(ws + 50331648);
  unsigned short* Wkt  = (unsigned short*)(ws + 58720256);
  unsigned short* Wvt  = (unsigned short*)(ws + 60817408);
  unsigned short* Wot  = (unsigned short*)(ws + 62914560);
  // xb (x converted to bf16, 32MB) lives in d_out (64MB) — dead until final GEMM.
  unsigned short* xb = (unsigned short*)d_out;

  cvt_f32_bf16<<<(B_ * T_ * DIM_) / (256 * 8), 256, 0, stream>>>(x, xb);

  transpose_f32_bf16<<<dim3(DIM_ / 32, DIM_ / 32), 256, 0, stream>>>(Wq, Wqt, DIM_, DIM_);
  transpose_f32_bf16<<<dim3(KVD_ / 32, DIM_ / 32), 256, 0, stream>>>(Wk, Wkt, DIM_, KVD_);
  transpose_f32_bf16<<<dim3(KVD_ / 32, DIM_ / 32), 256, 0, stream>>>(Wv, Wvt, DIM_, KVD_);
  transpose_f32_bf16<<<dim3(DIM_ / 32, DIM_ / 32), 256, 0, stream>>>(Wo, Wot, DIM_, DIM_);

  gemm_bt<false><<<dim3(DIM_ / 128, (B_ * T_) / 128), 256, 0, stream>>>(xb, Wqt, q_ws, B_ * T_, DIM_, DIM_);
  gemm_bt<false><<<dim3(KVD_ / 128, (B_ * T_) / 128), 256, 0, stream>>>(xb, Wkt, k_ws, B_ * T_, KVD_, DIM_);
  gemm_bt<false><<<dim3(KVD_ / 128, (B_ * T_) / 128), 256, 0, stream>>>(xb, Wvt, v_ws, B_ * T_, KVD_, DIM_);

  rope_kernel<<<(B_ * T_ * (H_ + KVH_)) / 4, 256, 0, stream>>>(q_ws, k_ws);

  attn_kernel<<<dim3(T_ / 64, B_ * H_), 256, 0, stream>>>(q_ws, k_ws, v_ws, q_ws);

  gemm_bt<true><<<dim3(DIM_ / 128, (B_ * T_) / 128), 256, 0, stream>>>(q_ws, Wot, out, B_ * T_, DIM_, DIM_);
}

// Round 4
// 547.670 us; speedup vs baseline: 1.3591x; 1.3591x over previous
//
#include <hip/hip_runtime.h>
#include <stdint.h>
#include <math.h>

#define DEV static __device__ __forceinline__

typedef __attribute__((ext_vector_type(8))) short short8;
typedef __attribute__((ext_vector_type(4))) float f32x4;

#define B_ 4
#define T_ 2048
#define H_ 16
#define KVH_ 4
#define HD_ 128
#define DIM_ 2048
#define KVD_ 512

DEV float bf2f(unsigned short h) {
  union { uint32_t u; float f; } v; v.u = ((uint32_t)h) << 16; return v.f;
}
DEV unsigned short f2bf(float f) {
  uint32_t u = __builtin_bit_cast(uint32_t, f);
  u += 0x7fffu + ((u >> 16) & 1u);   // round-to-nearest-even
  return (unsigned short)(u >> 16);
}
DEV void gll16(const void* g, void* l) {
  __builtin_amdgcn_global_load_lds(
      (const __attribute__((address_space(1))) unsigned int*)g,
      (__attribute__((address_space(3))) unsigned int*)l, 16, 0, 0);
}

// ---------------- fp32 -> bf16 convert (vectorized) ----------------
__global__ __launch_bounds__(256) void cvt_f32_bf16(
    const float* __restrict__ in, unsigned short* __restrict__ out) {
  size_t idx = ((size_t)blockIdx.x * 256 + threadIdx.x) * 8;
  float4 a = *(const float4*)(in + idx);
  float4 b = *(const float4*)(in + idx + 4);
  short8 o;
  o[0] = (short)f2bf(a.x); o[1] = (short)f2bf(a.y);
  o[2] = (short)f2bf(a.z); o[3] = (short)f2bf(a.w);
  o[4] = (short)f2bf(b.x); o[5] = (short)f2bf(b.y);
  o[6] = (short)f2bf(b.z); o[7] = (short)f2bf(b.w);
  *(short8*)(out + idx) = o;
}

// ---------------- transpose + convert: W fp32 [R][C] -> Wt bf16 [C][R] ----------------
__global__ __launch_bounds__(256) void transpose_f32_bf16(
    const float* __restrict__ W, unsigned short* __restrict__ Wt,
    int R, int C) {
  __shared__ float t[32][33];
  int c0 = blockIdx.x * 32, r0 = blockIdx.y * 32;
  int col = threadIdx.x & 31;
  int rr = (threadIdx.x >> 5) * 4;
#pragma unroll
  for (int i = 0; i < 4; ++i)
    t[rr + i][col] = W[(size_t)(r0 + rr + i) * C + c0 + col];
  __syncthreads();
#pragma unroll
  for (int i = 0; i < 4; ++i)
    Wt[(size_t)(c0 + rr + i) * R + r0 + col] = f2bf(t[col][rr + i]);
}

// ---------------- RoPE in-place (bf16); one wave per head-row ----------------
__global__ __launch_bounds__(256) void rope_kernel(unsigned short* q,
                                                   unsigned short* k) {
  int wid = blockIdx.x * 4 + (threadIdx.x >> 6);
  int lane = threadIdx.x & 63;
  const int NQ = B_ * T_ * H_;
  unsigned short* ptr;
  int t;
  if (wid < NQ) {
    int bt = wid >> 4, h = wid & (H_ - 1);
    ptr = q + (size_t)bt * DIM_ + h * HD_;
    t = bt & (T_ - 1);
  } else {
    int id = wid - NQ;
    int bt = id >> 2, g = id & (KVH_ - 1);
    ptr = k + (size_t)bt * KVD_ + g * HD_;
    t = bt & (T_ - 1);
  }
  float inv = __expf(-(float)lane * 0.14391157f);  // ln(10000)/64
  float ang = (float)t * inv;
  float s = sinf(ang), c = cosf(ang);
  uint32_t zz = *(const uint32_t*)(ptr + lane * 2);
  float z1 = bf2f((unsigned short)(zz & 0xffff));
  float z2 = bf2f((unsigned short)(zz >> 16));
  unsigned short o1 = f2bf(z1 * c - z2 * s);
  unsigned short o2 = f2bf(z1 * s + z2 * c);
  ptr[lane] = o1;
  ptr[64 + lane] = o2;
}

// ---------------- GEMM: C[M,N] = A[M,K] @ Bt[N,K]^T  (m97 structure) ----------------
template <bool OUT_F32>
__global__ __launch_bounds__(256) void gemm_bt(
    const unsigned short* __restrict__ A, const unsigned short* __restrict__ Bt,
    void* __restrict__ Cout, int M, int N, int K) {
  __shared__ unsigned short As[128 * 32];
  __shared__ unsigned short Bs[128 * 32];
  int m0 = blockIdx.y * 128, n0 = blockIdx.x * 128;
  int tid = threadIdx.x, w = tid >> 6, l = tid & 63;
  int wr = w >> 1, wc = w & 1;
  int l15 = l & 15, l4 = l >> 4;
  f32x4 acc[4][4] = {};
  for (int k0 = 0; k0 < K; k0 += 32) {
    __syncthreads();
#pragma unroll
    for (int i = 0; i < 2; ++i) {
      int u = i * 256 + w * 64 + l;
      int row = u >> 2, kc = u & 3;
      gll16(A + (size_t)(m0 + row) * K + k0 + kc * 8, As + (size_t)u * 8);
      gll16(Bt + (size_t)(n0 + row) * K + k0 + kc * 8, Bs + (size_t)u * 8);
    }
    __syncthreads();
    short8 a[4], b[4];
#pragma unroll
    for (int mb = 0; mb < 4; ++mb)
      a[mb] = *(const short8*)(As + ((wr * 64 + mb * 16 + l15) * 4 + l4) * 8);
#pragma unroll
    for (int nb = 0; nb < 4; ++nb)
      b[nb] = *(const short8*)(Bs + ((wc * 64 + nb * 16 + l15) * 4 + l4) * 8);
#pragma unroll
    for (int mb = 0; mb < 4; ++mb)
#pragma unroll
      for (int nb = 0; nb < 4; ++nb)
        acc[mb][nb] =
            __builtin_amdgcn_mfma_f32_16x16x32_bf16(a[mb], b[nb], acc[mb][nb], 0, 0, 0);
  }
#pragma unroll
  for (int mb = 0; mb < 4; ++mb)
#pragma unroll
    for (int nb = 0; nb < 4; ++nb)
#pragma unroll
      for (int r = 0; r < 4; ++r) {
        size_t off = (size_t)(m0 + wr * 64 + mb * 16 + l4 * 4 + r) * N +
                     n0 + wc * 64 + nb * 16 + l15;
        if (OUT_F32)
          ((float*)Cout)[off] = acc[mb][nb][r];
        else
          ((unsigned short*)Cout)[off] = f2bf(acc[mb][nb][r]);
      }
}

// ---------------- Flash attention v3 ----------------
// v1-verified compute layouts + 2-phase pipeline:
//   phase A: VLOAD(t+1) issue; QK^T from Ks; softmax; P->Ps[w]
//   barrier A (Ks free, Vt[1-cur] free)
//   STAGE_K(t+1) gll16; phase B: PV from Ps[w]+Vt[cur]; VWRITE(t+1)->Vt[1-cur]
//   barrier B (publish Ks(t+1), Vt(t+1))
// grid: x=bh, y: qt=31-y (true LPT, longest tiles dispatched first).
__global__ __launch_bounds__(256) void attn_kernel(
    const unsigned short* qws, const unsigned short* __restrict__ kws,
    const unsigned short* __restrict__ vws, unsigned short* ows) {
  int bh = blockIdx.x;
  int qt = 31 - (int)blockIdx.y;      // LPT
  int b = bh >> 4, h = bh & 15, g = h >> 2;
  int tid = threadIdx.x, w = tid >> 6, l = tid & 63;
  int l15 = l & 15, l4 = l >> 4;

  __shared__ unsigned short Ks[64 * 128];       // 16 KB, single
  __shared__ unsigned short Vt[2][128 * 64];    // 32 KB, double
  __shared__ unsigned short Ps[4][16 * 64];     // 8 KB, per-wave

  const unsigned short* kbase = kws + (size_t)(b * T_) * KVD_ + g * HD_;
  const unsigned short* vbase = vws + (size_t)(b * T_) * KVD_ + g * HD_;

  int q0w = qt * 64 + w * 16;
  short8 qf[4];
  {
    const unsigned short* qrow =
        qws + (size_t)(b * T_ + q0w + l15) * DIM_ + h * HD_ + l4 * 8;
#pragma unroll
    for (int kc = 0; kc < 4; ++kc) qf[kc] = *(const short8*)(qrow + kc * 32);
  }
  f32x4 o[8] = {};
  float m_r[4], l_r[4];
#pragma unroll
  for (int r = 0; r < 4; ++r) { m_r[r] = -INFINITY; l_r[r] = 0.f; }
  const float scale = 0.088388347648318447f;  // 1/sqrt(128)

#define STAGE_K(kt_)                                                     \
  {                                                                      \
    const unsigned short* kb = kbase + (size_t)(kt_) * 64 * KVD_;        \
    _Pragma("unroll") for (int i = 0; i < 4; ++i) {                      \
      int u = (i * 4 + w) * 64 + l;                                      \
      int row = u >> 4, c = u & 15;                                      \
      int kc = c ^ (row & 15);                                           \
      gll16(kb + (size_t)row * KVD_ + kc * 8, Ks + (size_t)u * 8);       \
    }                                                                    \
  }
#define VLOAD(kt_)                                                       \
  {                                                                      \
    const unsigned short* vrow = vbase + (size_t)((kt_) * 64 + l) * KVD_;\
    _Pragma("unroll") for (int i = 0; i < 4; ++i)                        \
      vg[i] = *(const short8*)(vrow + (w + i * 4) * 8);                  \
  }
#define VWRITE(buf_)                                                     \
  {                                                                      \
    _Pragma("unroll") for (int i = 0; i < 4; ++i) {                      \
      int dc = w + i * 4;                                                \
      _Pragma("unroll") for (int j = 0; j < 8; ++j)                      \
        Vt[buf_][(dc * 8 + j) * 64 + (((l >> 3) ^ j) << 3) + (l & 7)] =  \
            (unsigned short)vg[i][j];                                    \
    }                                                                    \
  }

  short8 vg[4];
  // prologue: stage tile 0
  STAGE_K(0);
  VLOAD(0);
  VWRITE(0);
  __syncthreads();   // publish Ks(0)+Vt(0); compiler drains vmcnt/lgkmcnt

  for (int kt = 0; kt <= qt; ++kt) {
    int cur = kt & 1;
    bool pre = (kt < qt);
    if (pre) VLOAD(kt + 1);           // T14: issue early, consume in phase B

    // ---- phase A: S = Q K^T  (rows q=w*16+l4*4+r, cols kv=nb*16+l15)
    f32x4 s[4];
    __builtin_amdgcn_s_setprio(1);
#pragma unroll
    for (int nb = 0; nb < 4; ++nb) {
      f32x4 acc = {};
#pragma unroll
      for (int kc = 0; kc < 4; ++kc) {
        int row = nb * 16 + l15;
        int c8 = (kc * 4 + l4) ^ (row & 15);
        short8 kf = *(const short8*)(Ks + (row * 16 + c8) * 8);
        acc = __builtin_amdgcn_mfma_f32_16x16x32_bf16(qf[kc], kf, acc, 0, 0, 0);
      }
      s[nb] = acc;
    }
    __builtin_amdgcn_s_setprio(0);
    bool diag = (kt == qt);
#pragma unroll
    for (int nb = 0; nb < 4; ++nb)
#pragma unroll
      for (int r = 0; r < 4; ++r) {
        float v = s[nb][r] * scale;
        if (diag && (nb * 16 + l15) > (w * 16 + l4 * 4 + r)) v = -1e30f;
        s[nb][r] = v;
      }
    // online softmax; row group = 16 lanes sharing l>>4
#pragma unroll
    for (int r = 0; r < 4; ++r) {
      float mx = fmaxf(fmaxf(s[0][r], s[1][r]), fmaxf(s[2][r], s[3][r]));
      mx = fmaxf(mx, __shfl_xor(mx, 1));
      mx = fmaxf(mx, __shfl_xor(mx, 2));
      mx = fmaxf(mx, __shfl_xor(mx, 4));
      mx = fmaxf(mx, __shfl_xor(mx, 8));
      float mnew = fmaxf(m_r[r], mx);
      float alpha = __expf(m_r[r] - mnew);
      m_r[r] = mnew;
      float sum = 0.f;
#pragma unroll
      for (int nb = 0; nb < 4; ++nb) {
        float p = __expf(s[nb][r] - mnew);
        s[nb][r] = p;
        sum += p;
      }
      sum += __shfl_xor(sum, 1);
      sum += __shfl_xor(sum, 2);
      sum += __shfl_xor(sum, 4);
      sum += __shfl_xor(sum, 8);
      l_r[r] = l_r[r] * alpha + sum;
#pragma unroll
      for (int db = 0; db < 8; ++db) o[db][r] *= alpha;
    }
    // P -> per-wave LDS (swizzled); no barrier needed (same-wave use)
    unsigned short* pws = Ps[w];
#pragma unroll
    for (int nb = 0; nb < 4; ++nb)
#pragma unroll
      for (int r = 0; r < 4; ++r) {
        int q = l4 * 4 + r;
        int kv = nb * 16 + l15;
        pws[q * 64 + (((kv >> 3) ^ (q & 7)) << 3) + (kv & 7)] = f2bf(s[nb][r]);
      }

    __syncthreads();                  // barrier A: Ks consumed, Vt[1-cur] free
    if (pre) STAGE_K(kt + 1);         // overlap K staging with PV

    // ---- phase B: PV from Ps[w] + Vt[cur]
    __builtin_amdgcn_s_setprio(1);
#pragma unroll
    for (int ks = 0; ks < 2; ++ks) {
      short8 pa = *(const short8*)(pws + l15 * 64 + (((ks * 4 + l4) ^ (l15 & 7)) << 3));
#pragma unroll
      for (int db = 0; db < 8; ++db) {
        int d = db * 16 + l15;
        short8 vb = *(const short8*)(Vt[cur] + d * 64 + (((ks * 4 + l4) ^ (d & 7)) << 3));
        o[db] = __builtin_amdgcn_mfma_f32_16x16x32_bf16(pa, vb, o[db], 0, 0, 0);
      }
    }
    __builtin_amdgcn_s_setprio(0);
    if (pre) VWRITE(1 - cur);         // transpose-write next V tile
    __syncthreads();                  // barrier B: publish Ks(kt+1)+Vt(kt+1)
  }
  // ---- epilogue
#pragma unroll
  for (int r = 0; r < 4; ++r) {
    float invl = 1.f / l_r[r];
    unsigned short* orow =
        ows + (size_t)(b * T_ + q0w + l4 * 4 + r) * DIM_ + h * HD_;
#pragma unroll
    for (int db = 0; db < 8; ++db) orow[db * 16 + l15] = f2bf(o[db][r] * invl);
  }
#undef STAGE_K
#undef VLOAD
#undef VWRITE
}

// ---------------- launch ----------------
extern "C" void kernel_launch(void* const* d_in, const int* in_sizes, int n_in,
                              void* d_out, int out_size, void* d_ws, size_t ws_size,
                              hipStream_t stream) {
  (void)in_sizes; (void)n_in; (void)out_size; (void)ws_size;
  const float* x  = (const float*)d_in[0];
  const float* Wq = (const float*)d_in[1];
  const float* Wk = (const float*)d_in[2];
  const float* Wv = (const float*)d_in[3];
  const float* Wo = (const float*)d_in[4];
  float* out = (float*)d_out;
  char* ws = (char*)d_ws;
  unsigned short* q_ws = (unsigned short*)(ws + 0);
  unsigned short* k_ws = (unsigned short*)(ws + 33554432);
  unsigned short* v_ws = (unsigned short*)(ws + 41943040);
  unsigned short* Wqt  = (unsigned short*)(ws + 50331648);
  unsigned short* Wkt  = (unsigned short*)(ws + 58720256);
  unsigned short* Wvt  = (unsigned short*)(ws + 60817408);
  unsigned short* Wot  = (unsigned short*)(ws + 62914560);
  unsigned short* xb = (unsigned short*)d_out;  // dead until final GEMM

  cvt_f32_bf16<<<(B_ * T_ * DIM_) / (256 * 8), 256, 0, stream>>>(x, xb);

  transpose_f32_bf16<<<dim3(DIM_ / 32, DIM_ / 32), 256, 0, stream>>>(Wq, Wqt, DIM_, DIM_);
  transpose_f32_bf16<<<dim3(KVD_ / 32, DIM_ / 32), 256, 0, stream>>>(Wk, Wkt, DIM_, KVD_);
  transpose_f32_bf16<<<dim3(KVD_ / 32, DIM_ / 32), 256, 0, stream>>>(Wv, Wvt, DIM_, KVD_);
  transpose_f32_bf16<<<dim3(DIM_ / 32, DIM_ / 32), 256, 0, stream>>>(Wo, Wot, DIM_, DIM_);

  gemm_bt<false><<<dim3(DIM_ / 128, (B_ * T_) / 128), 256, 0, stream>>>(xb, Wqt, q_ws, B_ * T_, DIM_, DIM_);
  gemm_bt<false><<<dim3(KVD_ / 128, (B_ * T_) / 128), 256, 0, stream>>>(xb, Wkt, k_ws, B_ * T_, KVD_, DIM_);
  gemm_bt<false><<<dim3(KVD_ / 128, (B_ * T_) / 128), 256, 0, stream>>>(xb, Wvt, v_ws, B_ * T_, KVD_, DIM_);

  rope_kernel<<<(B_ * T_ * (H_ + KVH_)) / 4, 256, 0, stream>>>(q_ws, k_ws);

  attn_kernel<<<dim3(B_ * H_, T_ / 64), 256, 0, stream>>>(q_ws, k_ws, v_ws, q_ws);

  gemm_bt<true><<<dim3(DIM_ / 128, (B_ * T_) / 128), 256, 0, stream>>>(q_ws, Wot, out, B_ * T_, DIM_, DIM_);
}

// Round 5
// 476.198 us; speedup vs baseline: 1.5631x; 1.1501x over previous
//
#include <hip/hip_runtime.h>
#include <stdint.h>
#include <math.h>

#define DEV static __device__ __forceinline__

typedef __attribute__((ext_vector_type(8))) short short8;
typedef __attribute__((ext_vector_type(4))) short short4v;
typedef __attribute__((ext_vector_type(4))) float f32x4;

#define B_ 4
#define T_ 2048
#define H_ 16
#define KVH_ 4
#define HD_ 128
#define DIM_ 2048
#define KVD_ 512

DEV float bf2f(unsigned short h) {
  union { uint32_t u; float f; } v; v.u = ((uint32_t)h) << 16; return v.f;
}
DEV unsigned short f2bf(float f) {
  uint32_t u = __builtin_bit_cast(uint32_t, f);
  u += 0x7fffu + ((u >> 16) & 1u);   // round-to-nearest-even
  return (unsigned short)(u >> 16);
}
DEV void gll16(const void* g, void* l) {
  __builtin_amdgcn_global_load_lds(
      (const __attribute__((address_space(1))) unsigned int*)g,
      (__attribute__((address_space(3))) unsigned int*)l, 16, 0, 0);
}

#if __has_builtin(__builtin_amdgcn_mfma_f32_16x16x16bf16_1k)
#define MFMA16(A, Bo, C) __builtin_amdgcn_mfma_f32_16x16x16bf16_1k((A), (Bo), (C), 0, 0, 0)
#else
DEV f32x4 mfma16_asm(short4v a, short4v b, f32x4 c) {
  asm volatile("v_mfma_f32_16x16x16_bf16 %0, %1, %2, %0" : "+v"(c) : "v"(a), "v"(b));
  return c;
}
#define MFMA16(A, Bo, C) mfma16_asm((A), (Bo), (C))
#endif

// ---------------- fp32 -> bf16 convert (vectorized) ----------------
__global__ __launch_bounds__(256) void cvt_f32_bf16(
    const float* __restrict__ in, unsigned short* __restrict__ out) {
  size_t idx = ((size_t)blockIdx.x * 256 + threadIdx.x) * 8;
  float4 a = *(const float4*)(in + idx);
  float4 b = *(const float4*)(in + idx + 4);
  short8 o;
  o[0] = (short)f2bf(a.x); o[1] = (short)f2bf(a.y);
  o[2] = (short)f2bf(a.z); o[3] = (short)f2bf(a.w);
  o[4] = (short)f2bf(b.x); o[5] = (short)f2bf(b.y);
  o[6] = (short)f2bf(b.z); o[7] = (short)f2bf(b.w);
  *(short8*)(out + idx) = o;
}

// ---------------- transpose + convert: W fp32 [R][C] -> Wt bf16 [C][R] ----------------
__global__ __launch_bounds__(256) void transpose_f32_bf16(
    const float* __restrict__ W, unsigned short* __restrict__ Wt,
    int R, int C) {
  __shared__ float t[32][33];
  int c0 = blockIdx.x * 32, r0 = blockIdx.y * 32;
  int col = threadIdx.x & 31;
  int rr = (threadIdx.x >> 5) * 4;
#pragma unroll
  for (int i = 0; i < 4; ++i)
    t[rr + i][col] = W[(size_t)(r0 + rr + i) * C + c0 + col];
  __syncthreads();
#pragma unroll
  for (int i = 0; i < 4; ++i)
    Wt[(size_t)(c0 + rr + i) * R + r0 + col] = f2bf(t[col][rr + i]);
}

// ---------------- RoPE in-place (bf16); one wave per head-row ----------------
__global__ __launch_bounds__(256) void rope_kernel(unsigned short* q,
                                                   unsigned short* k) {
  int wid = blockIdx.x * 4 + (threadIdx.x >> 6);
  int lane = threadIdx.x & 63;
  const int NQ = B_ * T_ * H_;
  unsigned short* ptr;
  int t;
  if (wid < NQ) {
    int bt = wid >> 4, h = wid & (H_ - 1);
    ptr = q + (size_t)bt * DIM_ + h * HD_;
    t = bt & (T_ - 1);
  } else {
    int id = wid - NQ;
    int bt = id >> 2, g = id & (KVH_ - 1);
    ptr = k + (size_t)bt * KVD_ + g * HD_;
    t = bt & (T_ - 1);
  }
  float inv = __expf(-(float)lane * 0.14391157f);  // ln(10000)/64
  float ang = (float)t * inv;
  float s = sinf(ang), c = cosf(ang);
  uint32_t zz = *(const uint32_t*)(ptr + lane * 2);
  float z1 = bf2f((unsigned short)(zz & 0xffff));
  float z2 = bf2f((unsigned short)(zz >> 16));
  unsigned short o1 = f2bf(z1 * c - z2 * s);
  unsigned short o2 = f2bf(z1 * s + z2 * c);
  ptr[lane] = o1;
  ptr[64 + lane] = o2;
}

// ---------------- GEMM: C[M,N] = A[M,K] @ Bt[N,K]^T  (m97 structure) ----------------
template <bool OUT_F32>
__global__ __launch_bounds__(256) void gemm_bt(
    const unsigned short* __restrict__ A, const unsigned short* __restrict__ Bt,
    void* __restrict__ Cout, int M, int N, int K) {
  __shared__ unsigned short As[128 * 32];
  __shared__ unsigned short Bs[128 * 32];
  int m0 = blockIdx.y * 128, n0 = blockIdx.x * 128;
  int tid = threadIdx.x, w = tid >> 6, l = tid & 63;
  int wr = w >> 1, wc = w & 1;
  int l15 = l & 15, l4 = l >> 4;
  f32x4 acc[4][4] = {};
  for (int k0 = 0; k0 < K; k0 += 32) {
    __syncthreads();
#pragma unroll
    for (int i = 0; i < 2; ++i) {
      int u = i * 256 + w * 64 + l;
      int row = u >> 2, kc = u & 3;
      gll16(A + (size_t)(m0 + row) * K + k0 + kc * 8, As + (size_t)u * 8);
      gll16(Bt + (size_t)(n0 + row) * K + k0 + kc * 8, Bs + (size_t)u * 8);
    }
    __syncthreads();
    short8 a[4], b[4];
#pragma unroll
    for (int mb = 0; mb < 4; ++mb)
      a[mb] = *(const short8*)(As + ((wr * 64 + mb * 16 + l15) * 4 + l4) * 8);
#pragma unroll
    for (int nb = 0; nb < 4; ++nb)
      b[nb] = *(const short8*)(Bs + ((wc * 64 + nb * 16 + l15) * 4 + l4) * 8);
#pragma unroll
    for (int mb = 0; mb < 4; ++mb)
#pragma unroll
      for (int nb = 0; nb < 4; ++nb)
        acc[mb][nb] =
            __builtin_amdgcn_mfma_f32_16x16x32_bf16(a[mb], b[nb], acc[mb][nb], 0, 0, 0);
  }
#pragma unroll
  for (int mb = 0; mb < 4; ++mb)
#pragma unroll
    for (int nb = 0; nb < 4; ++nb)
#pragma unroll
      for (int r = 0; r < 4; ++r) {
        size_t off = (size_t)(m0 + wr * 64 + mb * 16 + l4 * 4 + r) * N +
                     n0 + wc * 64 + nb * 16 + l15;
        if (OUT_F32)
          ((float*)Cout)[off] = acc[mb][nb][r];
        else
          ((unsigned short*)Cout)[off] = f2bf(acc[mb][nb][r]);
      }
}

// ---------------- Flash attention v4 ----------------
// Swapped QK^T (S^T in regs, q lane-local) -> in-register P as 16x16x16 PV
// B-operand; V^T fragments via ds_read_b64 from the v1-proven VWRITE swizzle;
// QBLK=128 (32 q/wave), KVBLK=64; defer-max; 2-phase pipeline (v3-proven).
__global__ __launch_bounds__(256, 2) void attn_kernel(
    const unsigned short* qws, const unsigned short* __restrict__ kws,
    const unsigned short* __restrict__ vws, unsigned short* ows) {
  int bh = blockIdx.x;
  int qt = 15 - (int)blockIdx.y;      // LPT: longest first
  int b = bh >> 4, h = bh & 15, g = h >> 2;
  int tid = threadIdx.x, w = tid >> 6, l = tid & 63;
  int l15 = l & 15, l4 = l >> 4;

  __shared__ unsigned short Ks[64 * 128];     // 16 KB single
  __shared__ unsigned short Vt[2][128 * 64];  // 32 KB double (V^T, swizzled)

  const unsigned short* kbase = kws + (size_t)(b * T_) * KVD_ + g * HD_;
  const unsigned short* vbase = vws + (size_t)(b * T_) * KVD_ + g * HD_;

  int q0 = qt * 128;
  int qw0 = q0 + w * 32;              // wave's first q row
  int qg = qw0 + l15;                 // lane's q row (qb adds 16)

  // Q fragments (B-operand): lane holds Q[qg + qb*16][k = kc*32 + l4*8 + i]
  short8 qf[2][4];
#pragma unroll
  for (int qb = 0; qb < 2; ++qb) {
    const unsigned short* qrow =
        qws + (size_t)(b * T_ + qg + qb * 16) * DIM_ + h * HD_ + l4 * 8;
#pragma unroll
    for (int kc = 0; kc < 4; ++kc) qf[qb][kc] = *(const short8*)(qrow + kc * 32);
  }

  f32x4 o[2][8] = {};
  float m[2], ls[2];
  m[0] = m[1] = -INFINITY;
  ls[0] = ls[1] = 0.f;
  const float scale = 0.088388347648318447f;  // 1/sqrt(128)

#define STAGE_K(kt_)                                                     \
  {                                                                      \
    const unsigned short* kb = kbase + (size_t)(kt_) * 64 * KVD_;        \
    _Pragma("unroll") for (int i = 0; i < 4; ++i) {                      \
      int u = (i * 4 + w) * 64 + l;                                      \
      int row = u >> 4, c = u & 15;                                      \
      int kc = c ^ (row & 15);                                           \
      gll16(kb + (size_t)row * KVD_ + kc * 8, Ks + (size_t)u * 8);       \
    }                                                                    \
  }
#define VLOAD(kt_)                                                       \
  {                                                                      \
    const unsigned short* vrow = vbase + (size_t)((kt_) * 64 + l) * KVD_;\
    _Pragma("unroll") for (int i = 0; i < 4; ++i)                        \
      vg[i] = *(const short8*)(vrow + (w + i * 4) * 8);                  \
  }
#define VWRITE(buf_)                                                     \
  {                                                                      \
    _Pragma("unroll") for (int i = 0; i < 4; ++i) {                      \
      int dc = w + i * 4;                                                \
      _Pragma("unroll") for (int j = 0; j < 8; ++j)                      \
        Vt[buf_][(dc * 8 + j) * 64 + (((l >> 3) ^ j) << 3) + (l & 7)] =  \
            (unsigned short)vg[i][j];                                    \
    }                                                                    \
  }

  short8 vg[4];
  STAGE_K(0);
  VLOAD(0);
  VWRITE(0);
  __syncthreads();   // publish Ks(0)+Vt(0)

  int nkt = 2 * qt + 2;
  for (int kt = 0; kt < nkt; ++kt) {
    int cur = kt & 1;
    bool pre = (kt + 1 < nkt);
    int kv0 = kt * 64;
    bool active = (kv0 <= qw0 + 31);  // any unmasked row in this wave?
    if (pre) VLOAD(kt + 1);           // issue early (T14)

    short4v pb[2][4];
    if (active) {
      // ---- QK^T swapped: s[qb][nb] = S^T, rows kv=kv0+nb*16+l4*4+r, col q
      f32x4 s[2][4];
      __builtin_amdgcn_s_setprio(1);
#pragma unroll
      for (int nb = 0; nb < 4; ++nb) {
        f32x4 a0 = {}, a1 = {};
#pragma unroll
        for (int kc = 0; kc < 4; ++kc) {
          int row = nb * 16 + l15;
          int c8 = (kc * 4 + l4) ^ l15;
          short8 kf = *(const short8*)(Ks + (row * 16 + c8) * 8);
          a0 = __builtin_amdgcn_mfma_f32_16x16x32_bf16(kf, qf[0][kc], a0, 0, 0, 0);
          a1 = __builtin_amdgcn_mfma_f32_16x16x32_bf16(kf, qf[1][kc], a1, 0, 0, 0);
        }
        s[0][nb] = a0;
        s[1][nb] = a1;
      }
      __builtin_amdgcn_s_setprio(0);
      // ---- scale + causal mask + online softmax (defer-max, THR=8)
      bool diag = (kv0 + 63 > qw0);
#pragma unroll
      for (int qb = 0; qb < 2; ++qb) {
        int qq = qg + qb * 16;
        float t = -INFINITY;
#pragma unroll
        for (int nb = 0; nb < 4; ++nb)
#pragma unroll
          for (int r = 0; r < 4; ++r) {
            float v = s[qb][nb][r] * scale;
            if (diag && (kv0 + nb * 16 + l4 * 4 + r) > qq) v = -1e30f;
            s[qb][nb][r] = v;
            t = fmaxf(t, v);
          }
        t = fmaxf(t, __shfl_xor(t, 16));
        t = fmaxf(t, __shfl_xor(t, 32));
        if (t > m[qb] + 8.f) {        // rescale only on significant growth
          float al = __expf(m[qb] - t);
          m[qb] = t;
          ls[qb] *= al;
#pragma unroll
          for (int db = 0; db < 8; ++db)
#pragma unroll
            for (int r = 0; r < 4; ++r) o[qb][db][r] *= al;
        }
        float sum = 0.f;
#pragma unroll
        for (int nb = 0; nb < 4; ++nb) {
          short4v pk;
#pragma unroll
          for (int r = 0; r < 4; ++r) {
            float p = __expf(s[qb][nb][r] - m[qb]);
            sum += p;
            pk[r] = (short)f2bf(p);
          }
          pb[qb][nb] = pk;
        }
        sum += __shfl_xor(sum, 16);
        sum += __shfl_xor(sum, 32);
        ls[qb] += sum;
      }
    }

    __syncthreads();                  // barrier A: Ks consumed by all waves
    if (pre) STAGE_K(kt + 1);         // overlap K staging with PV

    if (active) {
      // ---- PV: O^T += V^T · P^T  via 16x16x16 MFMA
      // a-frag: V^T[d = db*16 + l15][kv = nb*16 + l4*4 + i] from swizzled Vt
      __builtin_amdgcn_s_setprio(1);
#pragma unroll
      for (int db = 0; db < 8; ++db) {
        short4v vf[4];
#pragma unroll
        for (int nb = 0; nb < 4; ++nb) {
          int idx = (db * 16 + l15) * 64 +
                    (((nb * 2 + (l4 >> 1)) ^ (l15 & 7)) << 3) + ((l4 & 1) << 2);
          vf[nb] = *(const short4v*)(Vt[cur] + idx);
        }
#pragma unroll
        for (int qb = 0; qb < 2; ++qb)
#pragma unroll
          for (int nb = 0; nb < 4; ++nb)
            o[qb][db] = MFMA16(vf[nb], pb[qb][nb], o[qb][db]);
      }
      __builtin_amdgcn_s_setprio(0);
    }
    if (pre) VWRITE(1 - cur);         // transpose-write next V tile
    __syncthreads();                  // barrier B: publish Ks(kt+1)+Vt(kt+1)
  }

  // ---- epilogue: O[q][d = db*16 + l4*4 + r], 8B packed stores
#pragma unroll
  for (int qb = 0; qb < 2; ++qb) {
    float invl = 1.f / ls[qb];
    unsigned short* orow = ows + (size_t)(b * T_ + qg + qb * 16) * DIM_ + h * HD_;
#pragma unroll
    for (int db = 0; db < 8; ++db) {
      short4v pk;
#pragma unroll
      for (int r = 0; r < 4; ++r) pk[r] = (short)f2bf(o[qb][db][r] * invl);
      *(short4v*)(orow + db * 16 + l4 * 4) = pk;
    }
  }
#undef STAGE_K
#undef VLOAD
#undef VWRITE
}

// ---------------- launch ----------------
extern "C" void kernel_launch(void* const* d_in, const int* in_sizes, int n_in,
                              void* d_out, int out_size, void* d_ws, size_t ws_size,
                              hipStream_t stream) {
  (void)in_sizes; (void)n_in; (void)out_size; (void)ws_size;
  const float* x  = (const float*)d_in[0];
  const float* Wq = (const float*)d_in[1];
  const float* Wk = (const float*)d_in[2];
  const float* Wv = (const float*)d_in[3];
  const float* Wo = (const float*)d_in[4];
  float* out = (float*)d_out;
  char* ws = (char*)d_ws;
  unsigned short* q_ws = (unsigned short*)(ws + 0);
  unsigned short* k_ws = (unsigned short*)(ws + 33554432);
  unsigned short* v_ws = (unsigned short*)(ws + 41943040);
  unsigned short* Wqt  = (unsigned short*)(ws + 50331648);
  unsigned short* Wkt  = (unsigned short*)(ws + 58720256);
  unsigned short* Wvt  = (unsigned short*)(ws + 60817408);
  unsigned short* Wot  = (unsigned short*)(ws + 62914560);
  unsigned short* xb = (unsigned short*)d_out;  // dead until final GEMM

  cvt_f32_bf16<<<(B_ * T_ * DIM_) / (256 * 8), 256, 0, stream>>>(x, xb);

  transpose_f32_bf16<<<dim3(DIM_ / 32, DIM_ / 32), 256, 0, stream>>>(Wq, Wqt, DIM_, DIM_);
  transpose_f32_bf16<<<dim3(KVD_ / 32, DIM_ / 32), 256, 0, stream>>>(Wk, Wkt, DIM_, KVD_);
  transpose_f32_bf16<<<dim3(KVD_ / 32, DIM_ / 32), 256, 0, stream>>>(Wv, Wvt, DIM_, KVD_);
  transpose_f32_bf16<<<dim3(DIM_ / 32, DIM_ / 32), 256, 0, stream>>>(Wo, Wot, DIM_, DIM_);

  gemm_bt<false><<<dim3(DIM_ / 128, (B_ * T_) / 128), 256, 0, stream>>>(xb, Wqt, q_ws, B_ * T_, DIM_, DIM_);
  gemm_bt<false><<<dim3(KVD_ / 128, (B_ * T_) / 128), 256, 0, stream>>>(xb, Wkt, k_ws, B_ * T_, KVD_, DIM_);
  gemm_bt<false><<<dim3(KVD_ / 128, (B_ * T_) / 128), 256, 0, stream>>>(xb, Wvt, v_ws, B_ * T_, KVD_, DIM_);

  rope_kernel<<<(B_ * T_ * (H_ + KVH_)) / 4, 256, 0, stream>>>(q_ws, k_ws);

  attn_kernel<<<dim3(B_ * H_, T_ / 128), 256, 0, stream>>>(q_ws, k_ws, v_ws, q_ws);

  gemm_bt<true><<<dim3(DIM_ / 128, (B_ * T_) / 128), 256, 0, stream>>>(q_ws, Wot, out, B_ * T_, DIM_, DIM_);
}

// Round 6
// 450.024 us; speedup vs baseline: 1.6540x; 1.0582x over previous
//
#include <hip/hip_runtime.h>
#include <stdint.h>
#include <math.h>

#define DEV static __device__ __forceinline__

typedef __attribute__((ext_vector_type(8))) short short8;
typedef __attribute__((ext_vector_type(4))) short short4v;
typedef __attribute__((ext_vector_type(4))) float f32x4;

#define B_ 4
#define T_ 2048
#define H_ 16
#define KVH_ 4
#define HD_ 128
#define DIM_ 2048
#define KVD_ 512

DEV float bf2f(unsigned short h) {
  union { uint32_t u; float f; } v; v.u = ((uint32_t)h) << 16; return v.f;
}
DEV unsigned short f2bf(float f) {
  uint32_t u = __builtin_bit_cast(uint32_t, f);
  u += 0x7fffu + ((u >> 16) & 1u);   // round-to-nearest-even
  return (unsigned short)(u >> 16);
}
DEV void gll16(const void* g, void* l) {
  __builtin_amdgcn_global_load_lds(
      (const __attribute__((address_space(1))) unsigned int*)g,
      (__attribute__((address_space(3))) unsigned int*)l, 16, 0, 0);
}

#if __has_builtin(__builtin_amdgcn_mfma_f32_16x16x16bf16_1k)
#define MFMA16(A, Bo, C) __builtin_amdgcn_mfma_f32_16x16x16bf16_1k((A), (Bo), (C), 0, 0, 0)
#else
DEV f32x4 mfma16_asm(short4v a, short4v b, f32x4 c) {
  asm volatile("v_mfma_f32_16x16x16_bf16 %0, %1, %2, %0" : "+v"(c) : "v"(a), "v"(b));
  return c;
}
#define MFMA16(A, Bo, C) mfma16_asm((A), (Bo), (C))
#endif

// compiler-level + scheduler-level fence, then HW barrier (no vmcnt drain)
DEV void block_bar() {
  __builtin_amdgcn_sched_barrier(0);
  asm volatile("" ::: "memory");
  __builtin_amdgcn_s_barrier();
  asm volatile("" ::: "memory");
  __builtin_amdgcn_sched_barrier(0);
}

// ---------------- fp32 -> bf16 convert (vectorized) ----------------
__global__ __launch_bounds__(256) void cvt_f32_bf16(
    const float* __restrict__ in, unsigned short* __restrict__ out) {
  size_t idx = ((size_t)blockIdx.x * 256 + threadIdx.x) * 8;
  float4 a = *(const float4*)(in + idx);
  float4 b = *(const float4*)(in + idx + 4);
  short8 o;
  o[0] = (short)f2bf(a.x); o[1] = (short)f2bf(a.y);
  o[2] = (short)f2bf(a.z); o[3] = (short)f2bf(a.w);
  o[4] = (short)f2bf(b.x); o[5] = (short)f2bf(b.y);
  o[6] = (short)f2bf(b.z); o[7] = (short)f2bf(b.w);
  *(short8*)(out + idx) = o;
}

// ---------------- transpose + convert: W fp32 [R][C] -> Wt bf16 [C][R] ----------------
__global__ __launch_bounds__(256) void transpose_f32_bf16(
    const float* __restrict__ W, unsigned short* __restrict__ Wt,
    int R, int C) {
  __shared__ float t[32][33];
  int c0 = blockIdx.x * 32, r0 = blockIdx.y * 32;
  int col = threadIdx.x & 31;
  int rr = (threadIdx.x >> 5) * 4;
#pragma unroll
  for (int i = 0; i < 4; ++i)
    t[rr + i][col] = W[(size_t)(r0 + rr + i) * C + c0 + col];
  __syncthreads();
#pragma unroll
  for (int i = 0; i < 4; ++i)
    Wt[(size_t)(c0 + rr + i) * R + r0 + col] = f2bf(t[col][rr + i]);
}

// ---------------- RoPE in-place (bf16); one wave per head-row ----------------
__global__ __launch_bounds__(256) void rope_kernel(unsigned short* q,
                                                   unsigned short* k) {
  int wid = blockIdx.x * 4 + (threadIdx.x >> 6);
  int lane = threadIdx.x & 63;
  const int NQ = B_ * T_ * H_;
  unsigned short* ptr;
  int t;
  if (wid < NQ) {
    int bt = wid >> 4, h = wid & (H_ - 1);
    ptr = q + (size_t)bt * DIM_ + h * HD_;
    t = bt & (T_ - 1);
  } else {
    int id = wid - NQ;
    int bt = id >> 2, g = id & (KVH_ - 1);
    ptr = k + (size_t)bt * KVD_ + g * HD_;
    t = bt & (T_ - 1);
  }
  float inv = __expf(-(float)lane * 0.14391157f);  // ln(10000)/64
  float ang = (float)t * inv;
  float s = sinf(ang), c = cosf(ang);
  uint32_t zz = *(const uint32_t*)(ptr + lane * 2);
  float z1 = bf2f((unsigned short)(zz & 0xffff));
  float z2 = bf2f((unsigned short)(zz >> 16));
  unsigned short o1 = f2bf(z1 * c - z2 * s);
  unsigned short o2 = f2bf(z1 * s + z2 * c);
  ptr[lane] = o1;
  ptr[64 + lane] = o2;
}

// ---------------- GEMM 128² (m97 structure) — used for K/V proj ----------------
template <bool OUT_F32>
__global__ __launch_bounds__(256) void gemm_bt(
    const unsigned short* __restrict__ A, const unsigned short* __restrict__ Bt,
    void* __restrict__ Cout, int M, int N, int K) {
  __shared__ unsigned short As[128 * 32];
  __shared__ unsigned short Bs[128 * 32];
  int m0 = blockIdx.y * 128, n0 = blockIdx.x * 128;
  int tid = threadIdx.x, w = tid >> 6, l = tid & 63;
  int wr = w >> 1, wc = w & 1;
  int l15 = l & 15, l4 = l >> 4;
  f32x4 acc[4][4] = {};
  for (int k0 = 0; k0 < K; k0 += 32) {
    __syncthreads();
#pragma unroll
    for (int i = 0; i < 2; ++i) {
      int u = i * 256 + w * 64 + l;
      int row = u >> 2, kc = u & 3;
      gll16(A + (size_t)(m0 + row) * K + k0 + kc * 8, As + (size_t)u * 8);
      gll16(Bt + (size_t)(n0 + row) * K + k0 + kc * 8, Bs + (size_t)u * 8);
    }
    __syncthreads();
    short8 a[4], b[4];
#pragma unroll
    for (int mb = 0; mb < 4; ++mb)
      a[mb] = *(const short8*)(As + ((wr * 64 + mb * 16 + l15) * 4 + l4) * 8);
#pragma unroll
    for (int nb = 0; nb < 4; ++nb)
      b[nb] = *(const short8*)(Bs + ((wc * 64 + nb * 16 + l15) * 4 + l4) * 8);
#pragma unroll
    for (int mb = 0; mb < 4; ++mb)
#pragma unroll
      for (int nb = 0; nb < 4; ++nb)
        acc[mb][nb] =
            __builtin_amdgcn_mfma_f32_16x16x32_bf16(a[mb], b[nb], acc[mb][nb], 0, 0, 0);
  }
#pragma unroll
  for (int mb = 0; mb < 4; ++mb)
#pragma unroll
    for (int nb = 0; nb < 4; ++nb)
#pragma unroll
      for (int r = 0; r < 4; ++r) {
        size_t off = (size_t)(m0 + wr * 64 + mb * 16 + l4 * 4 + r) * N +
                     n0 + wc * 64 + nb * 16 + l15;
        if (OUT_F32)
          ((float*)Cout)[off] = acc[mb][nb][r];
        else
          ((unsigned short*)Cout)[off] = f2bf(acc[mb][nb][r]);
      }
}

// ---------------- GEMM 256² deep-pipeline (T2+T3+T4+T5) ----------------
// 512 thr = 8 waves (2M x 4N), per-wave C = 128x64. BK=32, 4-buffer LDS ring
// (128 KB), prefetch 3 tiles, counted vmcnt(8) once per tile, raw s_barrier.
// LDS swizzle: conceptual byte ba = row*64 + kbyte; stored at ba ^ ((ba>>7)&3)<<4
// (write side via pre-swizzled global source; read side same XOR).
template <bool OUT_F32>
__global__ __launch_bounds__(512, 2) void gemm256_bt(
    const unsigned short* __restrict__ A, const unsigned short* __restrict__ Bt,
    void* __restrict__ Cout, int M, int N, int K) {
  __shared__ unsigned short As[4][256 * 32];
  __shared__ unsigned short Bs[4][256 * 32];
  int tid = threadIdx.x, w = tid >> 6, l = tid & 63;
  int wm = w >> 2, wn = w & 3;
  int l15 = l & 15, l4 = l >> 4;
  int nx = N >> 8;
  // XCD-aware swizzle (grid multiple of 8)
  int cpx = (int)gridDim.x >> 3;
  int id = ((int)blockIdx.x & 7) * cpx + ((int)blockIdx.x >> 3);
  int bx = id % nx, by = id / nx;
  int m0 = by * 256, n0 = bx * 256;
  int nt = K >> 5;

  // staging source pre-swizzle: thread stages bytes u..u+15 (u = tid*16) of
  // each 8KB half; conceptual position ba = u ^ ((u>>7)&3)<<4.
  int u0 = tid * 16;
  int ba0 = u0 ^ (((u0 >> 7) & 3) << 4);
  int r0 = ba0 >> 6;            // row 0..127 (half 1 adds 128)
  int c0 = (ba0 & 63) >> 1;     // element col {0,8,16,24}

  f32x4 acc[8][4] = {};

#define STAGE_T(tt_, buf_)                                               \
  {                                                                      \
    const unsigned short* a0 = A + (size_t)(m0 + r0) * K + (tt_) * 32 + c0; \
    gll16(a0, &As[buf_][tid * 8]);                                       \
    gll16(a0 + (size_t)128 * K, &As[buf_][4096 + tid * 8]);              \
    const unsigned short* b0 = Bt + (size_t)(n0 + r0) * K + (tt_) * 32 + c0; \
    gll16(b0, &Bs[buf_][tid * 8]);                                       \
    gll16(b0 + (size_t)128 * K, &Bs[buf_][4096 + tid * 8]);              \
  }

  // prologue: stage tiles 0,1,2
#pragma unroll
  for (int tt = 0; tt < 3; ++tt) STAGE_T(tt, tt);
  asm volatile("s_waitcnt vmcnt(8)" ::: "memory");  // tile 0 landed
  block_bar();

#pragma unroll 4
  for (int t = 0; t < nt; ++t) {
    int buf = t & 3;
    int pf = t + 3;
    bool dopf = pf < nt;
    int pbuf = pf & 3;

    // ---- phase 0: issue A-gloads(t+3); read B-frags + A-frags mf0-3; MFMA
    if (dopf) {
      const unsigned short* a0 = A + (size_t)(m0 + r0) * K + pf * 32 + c0;
      gll16(a0, &As[pbuf][tid * 8]);
      gll16(a0 + (size_t)128 * K, &As[pbuf][4096 + tid * 8]);
    }
    short8 bfr[4], afr[4];
#pragma unroll
    for (int nf = 0; nf < 4; ++nf) {
      int row = wn * 64 + nf * 16 + l15;
      bfr[nf] = *(const short8*)(&Bs[buf][row * 32 + ((l4 ^ ((row >> 1) & 3)) << 3)]);
    }
#pragma unroll
    for (int mf = 0; mf < 4; ++mf) {
      int row = wm * 128 + mf * 16 + l15;
      afr[mf] = *(const short8*)(&As[buf][row * 32 + ((l4 ^ ((row >> 1) & 3)) << 3)]);
    }
    asm volatile("s_waitcnt lgkmcnt(0)" ::: "memory");
    __builtin_amdgcn_sched_barrier(0);
    __builtin_amdgcn_s_setprio(1);
#pragma unroll
    for (int mf = 0; mf < 4; ++mf)
#pragma unroll
      for (int nf = 0; nf < 4; ++nf)
        acc[mf][nf] =
            __builtin_amdgcn_mfma_f32_16x16x32_bf16(afr[mf], bfr[nf], acc[mf][nf], 0, 0, 0);
    __builtin_amdgcn_s_setprio(0);
    block_bar();

    // ---- phase 1: issue B-gloads(t+3); read A-frags mf4-7; MFMA
    if (dopf) {
      const unsigned short* b0 = Bt + (size_t)(n0 + r0) * K + pf * 32 + c0;
      gll16(b0, &Bs[pbuf][tid * 8]);
      gll16(b0 + (size_t)128 * K, &Bs[pbuf][4096 + tid * 8]);
    }
    short8 afr2[4];
#pragma unroll
    for (int mf = 0; mf < 4; ++mf) {
      int row = wm * 128 + 64 + mf * 16 + l15;
      afr2[mf] = *(const short8*)(&As[buf][row * 32 + ((l4 ^ ((row >> 1) & 3)) << 3)]);
    }
    asm volatile("s_waitcnt lgkmcnt(0)" ::: "memory");
    __builtin_amdgcn_sched_barrier(0);
    __builtin_amdgcn_s_setprio(1);
#pragma unroll
    for (int mf = 0; mf < 4; ++mf)
#pragma unroll
      for (int nf = 0; nf < 4; ++nf)
        acc[4 + mf][nf] =
            __builtin_amdgcn_mfma_f32_16x16x32_bf16(afr2[mf], bfr[nf], acc[4 + mf][nf], 0, 0, 0);
    __builtin_amdgcn_s_setprio(0);
    asm volatile("s_waitcnt vmcnt(8)" ::: "memory");  // tile t+1 ready
    block_bar();
  }

  // ---- epilogue
#pragma unroll
  for (int mf = 0; mf < 8; ++mf)
#pragma unroll
    for (int nf = 0; nf < 4; ++nf)
#pragma unroll
      for (int r = 0; r < 4; ++r) {
        size_t off = (size_t)(m0 + wm * 128 + mf * 16 + l4 * 4 + r) * N +
                     n0 + wn * 64 + nf * 16 + l15;
        if (OUT_F32)
          ((float*)Cout)[off] = acc[mf][nf][r];
        else
          ((unsigned short*)Cout)[off] = f2bf(acc[mf][nf][r]);
      }
#undef STAGE_T
}

// ---------------- Flash attention v4 (unchanged from R5) ----------------
__global__ __launch_bounds__(256, 2) void attn_kernel(
    const unsigned short* qws, const unsigned short* __restrict__ kws,
    const unsigned short* __restrict__ vws, unsigned short* ows) {
  int bh = blockIdx.x;
  int qt = 15 - (int)blockIdx.y;      // LPT: longest first
  int b = bh >> 4, h = bh & 15, g = h >> 2;
  int tid = threadIdx.x, w = tid >> 6, l = tid & 63;
  int l15 = l & 15, l4 = l >> 4;

  __shared__ unsigned short Ks[64 * 128];     // 16 KB single
  __shared__ unsigned short Vt[2][128 * 64];  // 32 KB double (V^T, swizzled)

  const unsigned short* kbase = kws + (size_t)(b * T_) * KVD_ + g * HD_;
  const unsigned short* vbase = vws + (size_t)(b * T_) * KVD_ + g * HD_;

  int q0 = qt * 128;
  int qw0 = q0 + w * 32;              // wave's first q row
  int qg = qw0 + l15;                 // lane's q row (qb adds 16)

  short8 qf[2][4];
#pragma unroll
  for (int qb = 0; qb < 2; ++qb) {
    const unsigned short* qrow =
        qws + (size_t)(b * T_ + qg + qb * 16) * DIM_ + h * HD_ + l4 * 8;
#pragma unroll
    for (int kc = 0; kc < 4; ++kc) qf[qb][kc] = *(const short8*)(qrow + kc * 32);
  }

  f32x4 o[2][8] = {};
  float m[2], ls[2];
  m[0] = m[1] = -INFINITY;
  ls[0] = ls[1] = 0.f;
  const float scale = 0.088388347648318447f;  // 1/sqrt(128)

#define STAGE_K(kt_)                                                     \
  {                                                                      \
    const unsigned short* kb = kbase + (size_t)(kt_) * 64 * KVD_;        \
    _Pragma("unroll") for (int i = 0; i < 4; ++i) {                      \
      int u = (i * 4 + w) * 64 + l;                                      \
      int row = u >> 4, c = u & 15;                                      \
      int kc = c ^ (row & 15);                                           \
      gll16(kb + (size_t)row * KVD_ + kc * 8, Ks + (size_t)u * 8);       \
    }                                                                    \
  }
#define VLOAD(kt_)                                                       \
  {                                                                      \
    const unsigned short* vrow = vbase + (size_t)((kt_) * 64 + l) * KVD_;\
    _Pragma("unroll") for (int i = 0; i < 4; ++i)                        \
      vg[i] = *(const short8*)(vrow + (w + i * 4) * 8);                  \
  }
#define VWRITE(buf_)                                                     \
  {                                                                      \
    _Pragma("unroll") for (int i = 0; i < 4; ++i) {                      \
      int dc = w + i * 4;                                                \
      _Pragma("unroll") for (int j = 0; j < 8; ++j)                      \
        Vt[buf_][(dc * 8 + j) * 64 + (((l >> 3) ^ j) << 3) + (l & 7)] =  \
            (unsigned short)vg[i][j];                                    \
    }                                                                    \
  }

  short8 vg[4];
  STAGE_K(0);
  VLOAD(0);
  VWRITE(0);
  __syncthreads();   // publish Ks(0)+Vt(0)

  int nkt = 2 * qt + 2;
  for (int kt = 0; kt < nkt; ++kt) {
    int cur = kt & 1;
    bool pre = (kt + 1 < nkt);
    int kv0 = kt * 64;
    bool active = (kv0 <= qw0 + 31);
    if (pre) VLOAD(kt + 1);

    short4v pb[2][4];
    if (active) {
      f32x4 s[2][4];
      __builtin_amdgcn_s_setprio(1);
#pragma unroll
      for (int nb = 0; nb < 4; ++nb) {
        f32x4 a0 = {}, a1 = {};
#pragma unroll
        for (int kc = 0; kc < 4; ++kc) {
          int row = nb * 16 + l15;
          int c8 = (kc * 4 + l4) ^ l15;
          short8 kf = *(const short8*)(Ks + (row * 16 + c8) * 8);
          a0 = __builtin_amdgcn_mfma_f32_16x16x32_bf16(kf, qf[0][kc], a0, 0, 0, 0);
          a1 = __builtin_amdgcn_mfma_f32_16x16x32_bf16(kf, qf[1][kc], a1, 0, 0, 0);
        }
        s[0][nb] = a0;
        s[1][nb] = a1;
      }
      __builtin_amdgcn_s_setprio(0);
      bool diag = (kv0 + 63 > qw0);
#pragma unroll
      for (int qb = 0; qb < 2; ++qb) {
        int qq = qg + qb * 16;
        float t = -INFINITY;
#pragma unroll
        for (int nb = 0; nb < 4; ++nb)
#pragma unroll
          for (int r = 0; r < 4; ++r) {
            float v = s[qb][nb][r] * scale;
            if (diag && (kv0 + nb * 16 + l4 * 4 + r) > qq) v = -1e30f;
            s[qb][nb][r] = v;
            t = fmaxf(t, v);
          }
        t = fmaxf(t, __shfl_xor(t, 16));
        t = fmaxf(t, __shfl_xor(t, 32));
        if (t > m[qb] + 8.f) {
          float al = __expf(m[qb] - t);
          m[qb] = t;
          ls[qb] *= al;
#pragma unroll
          for (int db = 0; db < 8; ++db)
#pragma unroll
            for (int r = 0; r < 4; ++r) o[qb][db][r] *= al;
        }
        float sum = 0.f;
#pragma unroll
        for (int nb = 0; nb < 4; ++nb) {
          short4v pk;
#pragma unroll
          for (int r = 0; r < 4; ++r) {
            float p = __expf(s[qb][nb][r] - m[qb]);
            sum += p;
            pk[r] = (short)f2bf(p);
          }
          pb[qb][nb] = pk;
        }
        sum += __shfl_xor(sum, 16);
        sum += __shfl_xor(sum, 32);
        ls[qb] += sum;
      }
    }

    __syncthreads();
    if (pre) STAGE_K(kt + 1);

    if (active) {
      __builtin_amdgcn_s_setprio(1);
#pragma unroll
      for (int db = 0; db < 8; ++db) {
        short4v vf[4];
#pragma unroll
        for (int nb = 0; nb < 4; ++nb) {
          int idx = (db * 16 + l15) * 64 +
                    (((nb * 2 + (l4 >> 1)) ^ (l15 & 7)) << 3) + ((l4 & 1) << 2);
          vf[nb] = *(const short4v*)(Vt[cur] + idx);
        }
#pragma unroll
        for (int qb = 0; qb < 2; ++qb)
#pragma unroll
          for (int nb = 0; nb < 4; ++nb)
            o[qb][db] = MFMA16(vf[nb], pb[qb][nb], o[qb][db]);
      }
      __builtin_amdgcn_s_setprio(0);
    }
    if (pre) VWRITE(1 - cur);
    __syncthreads();
  }

#pragma unroll
  for (int qb = 0; qb < 2; ++qb) {
    float invl = 1.f / ls[qb];
    unsigned short* orow = ows + (size_t)(b * T_ + qg + qb * 16) * DIM_ + h * HD_;
#pragma unroll
    for (int db = 0; db < 8; ++db) {
      short4v pk;
#pragma unroll
      for (int r = 0; r < 4; ++r) pk[r] = (short)f2bf(o[qb][db][r] * invl);
      *(short4v*)(orow + db * 16 + l4 * 4) = pk;
    }
  }
#undef STAGE_K
#undef VLOAD
#undef VWRITE
}

// ---------------- launch ----------------
extern "C" void kernel_launch(void* const* d_in, const int* in_sizes, int n_in,
                              void* d_out, int out_size, void* d_ws, size_t ws_size,
                              hipStream_t stream) {
  (void)in_sizes; (void)n_in; (void)out_size; (void)ws_size;
  const float* x  = (const float*)d_in[0];
  const float* Wq = (const float*)d_in[1];
  const float* Wk = (const float*)d_in[2];
  const float* Wv = (const float*)d_in[3];
  const float* Wo = (const float*)d_in[4];
  float* out = (float*)d_out;
  char* ws = (char*)d_ws;
  unsigned short* q_ws = (unsigned short*)(ws + 0);
  unsigned short* k_ws = (unsigned short*)(ws + 33554432);
  unsigned short* v_ws = (unsigned short*)(ws + 41943040);
  unsigned short* Wqt  = (unsigned short*)(ws + 50331648);
  unsigned short* Wkt  = (unsigned short*)(ws + 58720256);
  unsigned short* Wvt  = (unsigned short*)(ws + 60817408);
  unsigned short* Wot  = (unsigned short*)(ws + 62914560);
  unsigned short* xb = (unsigned short*)d_out;  // dead until final GEMM

  cvt_f32_bf16<<<(B_ * T_ * DIM_) / (256 * 8), 256, 0, stream>>>(x, xb);

  transpose_f32_bf16<<<dim3(DIM_ / 32, DIM_ / 32), 256, 0, stream>>>(Wq, Wqt, DIM_, DIM_);
  transpose_f32_bf16<<<dim3(KVD_ / 32, DIM_ / 32), 256, 0, stream>>>(Wk, Wkt, DIM_, KVD_);
  transpose_f32_bf16<<<dim3(KVD_ / 32, DIM_ / 32), 256, 0, stream>>>(Wv, Wvt, DIM_, KVD_);
  transpose_f32_bf16<<<dim3(DIM_ / 32, DIM_ / 32), 256, 0, stream>>>(Wo, Wot, DIM_, DIM_);

  gemm256_bt<false><<<(DIM_ / 256) * ((B_ * T_) / 256), 512, 0, stream>>>(
      xb, Wqt, q_ws, B_ * T_, DIM_, DIM_);
  gemm_bt<false><<<dim3(KVD_ / 128, (B_ * T_) / 128), 256, 0, stream>>>(xb, Wkt, k_ws, B_ * T_, KVD_, DIM_);
  gemm_bt<false><<<dim3(KVD_ / 128, (B_ * T_) / 128), 256, 0, stream>>>(xb, Wvt, v_ws, B_ * T_, KVD_, DIM_);

  rope_kernel<<<(B_ * T_ * (H_ + KVH_)) / 4, 256, 0, stream>>>(q_ws, k_ws);

  attn_kernel<<<dim3(B_ * H_, T_ / 128), 256, 0, stream>>>(q_ws, k_ws, v_ws, q_ws);

  gemm256_bt<true><<<(DIM_ / 256) * ((B_ * T_) / 256), 512, 0, stream>>>(
      q_ws, Wot, out, B_ * T_, DIM_, DIM_);
}